// Round 2
// baseline (509.538 us; speedup 1.0000x reference)
//
#include <hip/hip_runtime.h>
#include <math.h>

#define T_TOK 16384
#define D_DIM 2048
#define NSLOT 64
#define H_DIM 1024
#define KSPLIT 8
#define KCH (D_DIM / KSPLIT)   // 256

// ---------------------------------------------------------------------------
// Kernel 1: partial logits, K-split. Block: 256 tokens x 64 slots, 256 thr.
// Thread: 8 tokens (tq + 32i) x 8 slots (sg + 8j). LDS XOR-swizzled so the
// strided ds_read_b128 per lane is bank-conflict-free.
// ---------------------------------------------------------------------------
__global__ __launch_bounds__(256) void k_logits(const float* __restrict__ x,
                                                const float* __restrict__ Wd,
                                                float* __restrict__ plog) {
    __shared__ float xs[256][32];
    __shared__ float ws[64][32];
    const int tid = threadIdx.x;
    const int tblk = blockIdx.x * 256;
    const int ks = blockIdx.y;
    const int koff = ks * KCH;
    const int tq = tid >> 3;   // 0..31
    const int sg = tid & 7;    // 0..7
    float acc[8][8] = {};

    for (int kc = 0; kc < KCH; kc += 32) {
        __syncthreads();
        // stage xs: 256x32 floats = 2048 float4, 8 per thread (swizzled cols)
        #pragma unroll
        for (int ii = 0; ii < 8; ++ii) {
            int fi = tid + ii * 256;
            int t = fi >> 3, c = fi & 7;
            *(float4*)&xs[t][(c ^ (t & 7)) << 2] =
                *(const float4*)&x[(size_t)(tblk + t) * D_DIM + koff + kc + c * 4];
        }
        // stage ws: 64x32 = 512 float4, 2 per thread
        #pragma unroll
        for (int ii = 0; ii < 2; ++ii) {
            int fi = tid + ii * 256;
            int s = fi >> 3, c = fi & 7;
            *(float4*)&ws[s][(c ^ (s & 7)) << 2] =
                *(const float4*)&Wd[(size_t)s * D_DIM + koff + kc + c * 4];
        }
        __syncthreads();
        #pragma unroll
        for (int c = 0; c < 8; ++c) {
            float4 wv[8];
            #pragma unroll
            for (int j = 0; j < 8; ++j)
                wv[j] = *(const float4*)&ws[sg + 8 * j][(c ^ sg) << 2];
            #pragma unroll
            for (int i = 0; i < 8; ++i) {
                float4 xv = *(const float4*)&xs[tq + 32 * i][(c ^ (tq & 7)) << 2];
                #pragma unroll
                for (int j = 0; j < 8; ++j)
                    acc[i][j] += xv.x * wv[j].x + xv.y * wv[j].y +
                                 xv.z * wv[j].z + xv.w * wv[j].w;
            }
        }
    }
    #pragma unroll
    for (int i = 0; i < 8; ++i)
        #pragma unroll
        for (int j = 0; j < 8; ++j)
            plog[((size_t)ks * T_TOK + tblk + tq + 32 * i) * NSLOT + sg + 8 * j] =
                acc[i][j];
}

// Kernel 2: sum K-split partials -> logits. grid 1024, block 256.
__global__ __launch_bounds__(256) void k_lsum(const float* __restrict__ plog,
                                              float* __restrict__ logits) {
    const size_t idx = ((size_t)blockIdx.x * 256 + threadIdx.x) * 4;
    float4 a = *(const float4*)&plog[idx];
    #pragma unroll
    for (int j = 1; j < KSPLIT; ++j) {
        float4 v = *(const float4*)&plog[(size_t)j * T_TOK * NSLOT + idx];
        a.x += v.x; a.y += v.y; a.z += v.z; a.w += v.w;
    }
    *(float4*)&logits[idx] = a;
}

// ---------------------------------------------------------------------------
// Kernel 3: per-(block,slot) partial column max / sum-exp. grid 64, block 256.
// ---------------------------------------------------------------------------
__global__ __launch_bounds__(256) void k_cred1(const float* __restrict__ logits,
                                               float* __restrict__ pm,
                                               float* __restrict__ pz) {
    __shared__ float lm[256], lz[256];
    const int tid = threadIdx.x;
    const size_t base = (size_t)blockIdx.x * 256 * NSLOT;
    float m = -1e30f, z = 0.f;
    for (int i = 0; i < 64; ++i) {
        float v = logits[base + (size_t)i * 256 + tid];
        float nm = fmaxf(m, v);
        z = z * __expf(m - nm) + __expf(v - nm);
        m = nm;
    }
    lm[tid] = m; lz[tid] = z;
    __syncthreads();
    if (tid < 64) {
        float M = lm[tid], Z = lz[tid];
        #pragma unroll
        for (int i = 1; i < 4; ++i) {
            float m2 = lm[tid + i * 64], z2 = lz[tid + i * 64];
            float nm = fmaxf(M, m2);
            Z = Z * __expf(M - nm) + z2 * __expf(m2 - nm);
            M = nm;
        }
        pm[blockIdx.x * NSLOT + tid] = M;
        pz[blockIdx.x * NSLOT + tid] = Z;
    }
}

// Kernel 4: final column softmax stats. 1 block, 64 threads.
__global__ void k_cred2(const float* __restrict__ pm, const float* __restrict__ pz,
                        float* __restrict__ m_out, float* __restrict__ invZ_out) {
    const int s = threadIdx.x;
    float M = -1e30f, Z = 0.f;
    for (int i = 0; i < 64; ++i) {
        float m2 = pm[i * NSLOT + s], z2 = pz[i * NSLOT + s];
        float nm = fmaxf(M, m2);
        Z = Z * __expf(M - nm) + z2 * __expf(m2 - nm);
        M = nm;
    }
    m_out[s] = M;
    invZ_out[s] = 1.f / Z;
}

// ---------------------------------------------------------------------------
// Kernel 5: materialize dispatch (col-softmax) & combine (row-softmax) probs.
// wave per token row; grid 4096, block 256.
// ---------------------------------------------------------------------------
__global__ __launch_bounds__(256) void k_probs(const float* __restrict__ logits,
                                               const float* __restrict__ mS,
                                               const float* __restrict__ invZ,
                                               float* __restrict__ disp,
                                               float* __restrict__ comb) {
    const int wave = threadIdx.x >> 6, lane = threadIdx.x & 63;
    const int t = blockIdx.x * 4 + wave;
    float v = logits[(size_t)t * NSLOT + lane];
    float M = v;
    #pragma unroll
    for (int off = 32; off; off >>= 1) M = fmaxf(M, __shfl_xor(M, off));
    float e = __expf(v - M);
    float Z = e;
    #pragma unroll
    for (int off = 32; off; off >>= 1) Z += __shfl_xor(Z, off);
    comb[(size_t)t * NSLOT + lane] = e / Z;
    disp[(size_t)t * NSLOT + lane] = __expf(v - mS[lane]) * invZ[lane];
}

// ---------------------------------------------------------------------------
// Kernel 6: partial slot_inputs. grid (8 d-tiles of 256, 64 t-chunks of 256).
// Thread: 8 slots x 8 d (two float4 columns). Uniform-row b128 xs reads.
// ---------------------------------------------------------------------------
__global__ __launch_bounds__(256) void k_slot_inputs(const float* __restrict__ x,
        const float* __restrict__ disp, float* __restrict__ partial) {
    __shared__ float xs[32][256];
    __shared__ float pls[32][64];
    const int tid = threadIdx.x;
    const int d0 = blockIdx.x * 256;
    const int tc0 = blockIdx.y * 256;
    const int dg = tid & 31;
    const int sgq = tid >> 5;   // 0..7
    float4 acc0[8] = {}, acc1[8] = {};

    for (int sub = 0; sub < 8; ++sub) {
        const int t0 = tc0 + sub * 32;
        __syncthreads();
        #pragma unroll
        for (int ii = 0; ii < 8; ++ii) {
            int fi = tid + ii * 256;
            int r = fi >> 6, c4 = fi & 63;
            *(float4*)&xs[r][c4 * 4] =
                *(const float4*)&x[(size_t)(t0 + r) * D_DIM + d0 + c4 * 4];
        }
        #pragma unroll
        for (int ii = 0; ii < 2; ++ii) {
            int fi = tid + ii * 256;
            int r = fi >> 4, s4 = fi & 15;
            *(float4*)&pls[r][s4 * 4] =
                *(const float4*)&disp[(size_t)(t0 + r) * NSLOT + s4 * 4];
        }
        __syncthreads();
        for (int t = 0; t < 32; ++t) {
            float4 xv0 = *(const float4*)&xs[t][dg * 4];
            float4 xv1 = *(const float4*)&xs[t][128 + dg * 4];
            #pragma unroll
            for (int i = 0; i < 8; ++i) {
                float p = pls[t][sgq * 8 + i];
                acc0[i].x += p * xv0.x; acc0[i].y += p * xv0.y;
                acc0[i].z += p * xv0.z; acc0[i].w += p * xv0.w;
                acc1[i].x += p * xv1.x; acc1[i].y += p * xv1.y;
                acc1[i].z += p * xv1.z; acc1[i].w += p * xv1.w;
            }
        }
    }
    #pragma unroll
    for (int i = 0; i < 8; ++i) {
        int s = sgq * 8 + i;
        *(float4*)&partial[((size_t)blockIdx.y * NSLOT + s) * D_DIM + d0 + dg * 4] = acc0[i];
        *(float4*)&partial[((size_t)blockIdx.y * NSLOT + s) * D_DIM + d0 + 128 + dg * 4] = acc1[i];
    }
}

// Kernel 7: reduce 64 t-chunk partials -> slot_in (64 x 2048). grid 128.
__global__ __launch_bounds__(256) void k_sred(const float* __restrict__ partial,
                                              float* __restrict__ slot_in) {
    const size_t idx = ((size_t)blockIdx.x * 256 + threadIdx.x) * 4;
    float4 a = {0.f, 0.f, 0.f, 0.f};
    for (int c = 0; c < 64; ++c) {
        float4 v = *(const float4*)&partial[(size_t)c * (NSLOT * D_DIM) + idx];
        a.x += v.x; a.y += v.y; a.z += v.z; a.w += v.w;
    }
    *(float4*)&slot_in[idx] = a;
}

// ---------------------------------------------------------------------------
// Kernel 8: h = gelu(W1 @ slot_in + b1). One wave per row.
// ---------------------------------------------------------------------------
__global__ __launch_bounds__(256) void k_mlp1(const float* __restrict__ W1,
                                              const float* __restrict__ b1,
                                              const float* __restrict__ slot_in,
                                              float* __restrict__ h) {
    const int wave = threadIdx.x >> 6, lane = threadIdx.x & 63;
    const int row = blockIdx.x * 4 + wave;           // e*1024 + j
    const int e = row >> 10;
    const float* wr = W1 + (size_t)row * D_DIM;
    const float* xr = slot_in + (size_t)e * D_DIM;
    float acc = 0.f;
    #pragma unroll
    for (int i = 0; i < 8; ++i) {
        int k = (lane + i * 64) * 4;
        float4 w4 = *(const float4*)(wr + k);
        float4 x4 = *(const float4*)(xr + k);
        acc += w4.x * x4.x + w4.y * x4.y + w4.z * x4.z + w4.w * x4.w;
    }
    #pragma unroll
    for (int off = 32; off; off >>= 1) acc += __shfl_xor(acc, off);
    if (lane == 0) {
        float v = acc + b1[row];
        h[row] = 0.5f * v * (1.f + erff(v * 0.70710678118654752f));
    }
}

// Kernel 9: slot_out = W2 @ h + b2. One wave per row.
__global__ __launch_bounds__(256) void k_mlp2(const float* __restrict__ W2,
                                              const float* __restrict__ b2,
                                              const float* __restrict__ h,
                                              float* __restrict__ slot_out) {
    const int wave = threadIdx.x >> 6, lane = threadIdx.x & 63;
    const int row = blockIdx.x * 4 + wave;           // e*2048 + d
    const int e = row >> 11;
    const float* wr = W2 + (size_t)row * H_DIM;
    const float* xr = h + (size_t)e * H_DIM;
    float acc = 0.f;
    #pragma unroll
    for (int i = 0; i < 4; ++i) {
        int k = (lane + i * 64) * 4;
        float4 w4 = *(const float4*)(wr + k);
        float4 x4 = *(const float4*)(xr + k);
        acc += w4.x * x4.x + w4.y * x4.y + w4.z * x4.z + w4.w * x4.w;
    }
    #pragma unroll
    for (int off = 32; off; off >>= 1) acc += __shfl_xor(acc, off);
    if (lane == 0) slot_out[row] = acc + b2[row];
}

// ---------------------------------------------------------------------------
// Kernel 10: y = comb @ slot_out. Block: 128 tok x 128 d; thread 8 tok x 8 d.
// grid (16, 128).
// ---------------------------------------------------------------------------
__global__ __launch_bounds__(256) void k_combine(const float* __restrict__ comb,
                                                 const float* __restrict__ so,
                                                 float* __restrict__ y) {
    __shared__ float cl[128][68];
    __shared__ float sol[64][128];
    const int tid = threadIdx.x;
    const int d0 = blockIdx.x * 128;
    const int tb = blockIdx.y * 128;
    const int tq = tid >> 4;    // 0..15
    const int dgq = tid & 15;   // 0..15
    // stage comb 128x64 (8 float4 each)
    #pragma unroll
    for (int ii = 0; ii < 8; ++ii) {
        int fi = tid + ii * 256;
        int r = fi >> 4, s4 = fi & 15;
        *(float4*)&cl[r][s4 * 4] =
            *(const float4*)&comb[(size_t)(tb + r) * NSLOT + s4 * 4];
    }
    // stage slot_out tile 64x128
    #pragma unroll
    for (int ii = 0; ii < 8; ++ii) {
        int fi = tid + ii * 256;
        int r = fi >> 5, c4 = fi & 31;
        *(float4*)&sol[r][c4 * 4] =
            *(const float4*)&so[(size_t)r * D_DIM + d0 + c4 * 4];
    }
    __syncthreads();
    float4 acc0[8] = {}, acc1[8] = {};
    for (int s = 0; s < 64; ++s) {
        float4 sv0 = *(const float4*)&sol[s][dgq * 4];
        float4 sv1 = *(const float4*)&sol[s][64 + dgq * 4];
        #pragma unroll
        for (int i = 0; i < 8; ++i) {
            float cv = cl[tq + 16 * i][s];
            acc0[i].x += cv * sv0.x; acc0[i].y += cv * sv0.y;
            acc0[i].z += cv * sv0.z; acc0[i].w += cv * sv0.w;
            acc1[i].x += cv * sv1.x; acc1[i].y += cv * sv1.y;
            acc1[i].z += cv * sv1.z; acc1[i].w += cv * sv1.w;
        }
    }
    #pragma unroll
    for (int i = 0; i < 8; ++i) {
        *(float4*)&y[(size_t)(tb + tq + 16 * i) * D_DIM + d0 + dgq * 4] = acc0[i];
        *(float4*)&y[(size_t)(tb + tq + 16 * i) * D_DIM + d0 + 64 + dgq * 4] = acc1[i];
    }
}

// ---------------------------------------------------------------------------
extern "C" void kernel_launch(void* const* d_in, const int* in_sizes, int n_in,
                              void* d_out, int out_size, void* d_ws, size_t ws_size,
                              hipStream_t stream) {
    const float* x  = (const float*)d_in[0];
    const float* Wd = (const float*)d_in[1];
    const float* W1 = (const float*)d_in[2];
    const float* b1 = (const float*)d_in[3];
    const float* W2 = (const float*)d_in[4];
    const float* b2 = (const float*)d_in[5];
    float* y = (float*)d_out;

    float* w = (float*)d_ws;
    float* plog    = w;                                      // 8*16384*64 = 8,388,608
    float* logits  = plog + (size_t)KSPLIT * T_TOK * NSLOT;  // 1,048,576
    float* pm      = logits + (size_t)T_TOK * NSLOT;         // 4096
    float* pz      = pm + 64 * NSLOT;                        // 4096
    float* mS      = pz + 64 * NSLOT;                        // 64
    float* invZ    = mS + NSLOT;                             // 64
    float* disp    = invZ + NSLOT;                           // 1,048,576
    float* comb    = disp + (size_t)T_TOK * NSLOT;           // 1,048,576
    float* partial = comb + (size_t)T_TOK * NSLOT;           // 64*64*2048 = 8,388,608
    float* slot_in = partial + (size_t)64 * NSLOT * D_DIM;   // 131,072
    float* h       = slot_in + (size_t)NSLOT * D_DIM;        // 65,536
    float* slot_out= h + (size_t)NSLOT * H_DIM;              // 131,072

    k_logits<<<dim3(T_TOK / 256, KSPLIT), 256, 0, stream>>>(x, Wd, plog);
    k_lsum<<<(T_TOK * NSLOT) / (4 * 256), 256, 0, stream>>>(plog, logits);
    k_cred1<<<64, 256, 0, stream>>>(logits, pm, pz);
    k_cred2<<<1, 64, 0, stream>>>(pm, pz, mS, invZ);
    k_probs<<<T_TOK / 4, 256, 0, stream>>>(logits, mS, invZ, disp, comb);
    k_slot_inputs<<<dim3(8, 64), 256, 0, stream>>>(x, disp, partial);
    k_sred<<<(NSLOT * D_DIM) / (4 * 256), 256, 0, stream>>>(partial, slot_in);
    k_mlp1<<<(NSLOT * H_DIM) / 4, 256, 0, stream>>>(W1, b1, slot_in, h);
    k_mlp2<<<(NSLOT * D_DIM) / 4, 256, 0, stream>>>(W2, b2, h, slot_out);
    k_combine<<<dim3(16, 128), 256, 0, stream>>>(comb, slot_out, y);
}